// Round 3
// baseline (413.828 us; speedup 1.0000x reference)
//
#include <hip/hip_runtime.h>
#include <hip/hip_bf16.h>

typedef __attribute__((ext_vector_type(8))) short bf16x8;
typedef __attribute__((ext_vector_type(4))) float f32x4;
typedef __attribute__((ext_vector_type(4))) unsigned int u32x4;
typedef __attribute__((ext_vector_type(2))) unsigned int u32x2;

#define EPS 1e-5f

__device__ inline unsigned short f2bf(float x) {
  unsigned int u = __builtin_bit_cast(unsigned int, x);
  unsigned int r = (u + 0x7FFFu + ((u >> 16) & 1u)) >> 16;
  return (unsigned short)r;
}

__device__ inline unsigned int pk2(float a, float b) {
  return (unsigned int)f2bf(a) | ((unsigned int)f2bf(b) << 16);
}

// ---------------- prep: fold BN, pre-swizzle W1/W2 into MFMA fragment order ----------------
// ws layout: w1f bf16 [73728 B] | w2f bf16 [16384 B] | sc f32[384]
__global__ void prep_kernel(const float* __restrict__ W1, const float* __restrict__ W2,
                            const float* __restrict__ b1, const float* __restrict__ g1,
                            const float* __restrict__ be1, const float* __restrict__ m1,
                            const float* __restrict__ v1,
                            const float* __restrict__ b2, const float* __restrict__ g2,
                            const float* __restrict__ be2, const float* __restrict__ m2,
                            const float* __restrict__ v2,
                            unsigned short* __restrict__ w1f, unsigned short* __restrict__ w2f,
                            float* __restrict__ sc) {
  int t = blockIdx.x * 256 + threadIdx.x;
  if (t < 36864) {
    int j = t & 7, l = (t >> 3) & 63, f = t >> 9;
    int kb = f >> 3, nb = f & 7;
    int rk = kb * 32 + ((l >> 4) << 3) + j;
    int cn = (nb << 4) + (l & 15);
    w1f[t] = f2bf(W1[rk * 128 + cn]);
  } else if (t < 45056) {
    int o = t - 36864;
    int j = o & 7, l = (o >> 3) & 63, f = o >> 9;
    int kb = f >> 2, nb = f & 3;
    int rk = kb * 32 + ((l >> 4) << 3) + j;
    int cn = (nb << 4) + (l & 15);
    w2f[o] = f2bf(W2[rk * 64 + cn]);
  } else if (t < 45184) {
    int j = t - 45056;
    float s = g1[j] * rsqrtf(v1[j] + EPS);
    sc[j] = s;
    sc[128 + j] = (b1[j] - m1[j]) * s + be1[j];
  } else if (t < 45248) {
    int j = t - 45184;
    float s = g2[j] * rsqrtf(v2[j] + EPS);
    sc[256 + j] = s;
    sc[320 + j] = (b2[j] - m2[j]) * s + be2[j];
  }
}

// ---------------- fused main kernel (1024 threads = 16 waves) ----------------
// LDS map:
//   [0, 40960)        W1 frags kb4..8 (kb0..3 live in registers)
//   [40960, 43008)    SC (s1,c1,s2,c2,w3,b3)
//   [43008, 124928)   A-tile [128 rows x 640 B], XOR-swizzled
//   [124928, 157696)  x1 [128 rows x 256 B], XOR-swizzled
//   [157696, 158720)  l3 f32[256]
#define LDS_SC_OFF 40960
#define LDS_A_OFF 43008
#define LDS_X1_OFF 124928
#define LDS_L3_OFF 157696
#define LDS_TOTAL 158720

__global__ __launch_bounds__(1024, 4) void fused_kernel(
    const float* __restrict__ z, const int* __restrict__ ei, const float* __restrict__ ctx,
    const unsigned short* __restrict__ w1f, const unsigned short* __restrict__ w2f,
    const float* __restrict__ sc, const float* __restrict__ w3, const float* __restrict__ b3,
    float* __restrict__ out, int E, int nblk) {
  extern __shared__ char lds[];
  char* W1L = lds;
  float* SC = (float*)(lds + LDS_SC_OFF);
  char* AR = lds + LDS_A_OFF;
  char* X1 = lds + LDS_X1_OFF;
  float* l3 = (float*)(lds + LDS_L3_OFF);

  const int tid = threadIdx.x;
  const int lane = tid & 63, wave = tid >> 6;
  const int g = lane >> 4, lq = lane & 15;
  const int wr = wave >> 2, wc = wave & 3;   // L1 grid 4x4: 32 rows x 32 cols per wave
  const int w2r = wave >> 1, w2c = wave & 1; // L2 grid 8x2: 16 rows x 32 cols per wave
  const int sr = tid >> 3, sh = tid & 7;     // staging: 8 threads per edge
  const int grid = gridDim.x;

  // ---- stage W1 kb4..8 (40 KB) + SC into LDS ----
  {
    const f32x4* s = (const f32x4*)(w1f + 16384);
    f32x4* d = (f32x4*)W1L;
    d[tid] = s[tid];
    d[1024 + tid] = s[1024 + tid];
    if (tid < 512) d[2048 + tid] = s[2048 + tid];
    if (tid < 128) {
      SC[tid] = sc[tid];
      SC[128 + tid] = sc[128 + tid];
    } else if (tid < 192) {
      int j = tid - 128;
      SC[256 + j] = sc[256 + j];
      SC[320 + j] = sc[320 + j];
      SC[384 + j] = w3[j];
    } else if (tid == 192) {
      SC[448] = b3[0];
    }
  }

  // ---- persistent W fragments in registers ----
  bf16x8 w1r[4][2], w2g[4][2];
  {
    const bf16x8* W1G = (const bf16x8*)w1f;
    const bf16x8* W2G = (const bf16x8*)w2f;
#pragma unroll
    for (int kb = 0; kb < 4; kb++)
#pragma unroll
      for (int nf = 0; nf < 2; nf++) {
        w1r[kb][nf] = W1G[(kb * 8 + wc * 2 + nf) * 64 + lane];
        w2g[kb][nf] = W2G[(kb * 4 + w2c * 2 + nf) * 64 + lane];
      }
  }

  // ---- A-tile writer (from regs) ----
  f32x4 sv0, sv1, dv0, dv1, cv;
  int i0n, i1n;
  int t = blockIdx.x;

  auto writeA = [&]() {
    const int rswz = (sr & 7) << 4;
    char* rowp = AR + sr * 640;
    u32x4 ps = {pk2(sv0[0], sv0[1]), pk2(sv0[2], sv0[3]), pk2(sv1[0], sv1[1]), pk2(sv1[2], sv1[3])};
    u32x4 pd = {pk2(dv0[0], dv0[1]), pk2(dv0[2], dv0[3]), pk2(dv1[0], dv1[1]), pk2(dv1[2], dv1[3])};
    u32x4 pp = {pk2(sv0[0] * dv0[0], sv0[1] * dv0[1]), pk2(sv0[2] * dv0[2], sv0[3] * dv0[3]),
                pk2(sv1[0] * dv1[0], sv1[1] * dv1[1]), pk2(sv1[2] * dv1[2], sv1[3] * dv1[3])};
    u32x4 pa = {pk2(fabsf(sv0[0] - dv0[0]), fabsf(sv0[1] - dv0[1])),
                pk2(fabsf(sv0[2] - dv0[2]), fabsf(sv0[3] - dv0[3])),
                pk2(fabsf(sv1[0] - dv1[0]), fabsf(sv1[1] - dv1[1])),
                pk2(fabsf(sv1[2] - dv1[2]), fabsf(sv1[3] - dv1[3]))};
    u32x2 pc = {pk2(cv[0], cv[1]), pk2(cv[2], cv[3])};
    *(u32x4*)(rowp + ((sh * 16) ^ rswz)) = ps;
    *(u32x4*)(rowp + ((128 + sh * 16) ^ rswz)) = pd;
    *(u32x4*)(rowp + ((256 + sh * 16) ^ rswz)) = pp;
    *(u32x4*)(rowp + ((384 + sh * 16) ^ rswz)) = pa;
    *(u32x2*)(rowp + 512 + ((sh * 8) ^ rswz)) = pc;
  };
  auto gatherNext = [&](int tg) {  // load z/ctx for tile tg via i0n/i1n; prefetch ei for tg+grid
    const f32x4* zs = (const f32x4*)(z + ((size_t)i0n * 64 + sh * 8));
    sv0 = zs[0]; sv1 = zs[1];
    const f32x4* zd = (const f32x4*)(z + ((size_t)i1n * 64 + sh * 8));
    dv0 = zd[0]; dv1 = zd[1];
    int eg = (tg << 7) + sr;
    int esg = eg < E ? eg : E - 1;
    cv = *(const f32x4*)(ctx + (size_t)esg * 32 + sh * 4);
    int tn = tg + grid; if (tn >= nblk) tn = tg;
    int en = (tn << 7) + sr;
    int esn = en < E ? en : E - 1;
    i0n = ei[esn]; i1n = ei[E + esn];
  };

  // ---- prologue: gather tile t, write A(t), gather t+1, prefetch ei t+2 ----
  {
    int e = (t << 7) + sr;
    int es = e < E ? e : E - 1;
    int a0 = ei[es], a1 = ei[E + es];
    cv = *(const f32x4*)(ctx + (size_t)es * 32 + sh * 4);
    const f32x4* zs = (const f32x4*)(z + ((size_t)a0 * 64 + sh * 8));
    sv0 = zs[0]; sv1 = zs[1];
    const f32x4* zd = (const f32x4*)(z + ((size_t)a1 * 64 + sh * 8));
    dv0 = zd[0]; dv1 = zd[1];
    int tn = t + grid; if (tn >= nblk) tn = t;
    int en = (tn << 7) + sr;
    int esn = en < E ? en : E - 1;
    i0n = ei[esn]; i1n = ei[E + esn];
  }
  writeA();
  {
    int tn = t + grid; if (tn >= nblk) tn = t;
    gatherNext(tn);
  }
  __syncthreads();  // A(t) + W1L + SC visible

  for (; t < nblk; t += grid) {
    // ---- layer 1: A[128x288] @ W1[288x128]; 2x2 16x16 frags per wave ----
    f32x4 acc[2][2];
#pragma unroll
    for (int mf = 0; mf < 2; mf++)
#pragma unroll
      for (int nf = 0; nf < 2; nf++) {
        f32x4 zv = {0.f, 0.f, 0.f, 0.f};
        acc[mf][nf] = zv;
      }
    const bf16x8* W1F = (const bf16x8*)W1L;
#pragma unroll
    for (int kb = 0; kb < 9; kb++) {
      bf16x8 a[2], b[2];
#pragma unroll
      for (int mf = 0; mf < 2; mf++) {
        int row = wr * 32 + mf * 16 + lq;
        a[mf] = *(const bf16x8*)(AR + row * 640 + ((kb * 64 + g * 16) ^ ((row & 7) << 4)));
      }
      if (kb < 4) {
        b[0] = w1r[kb][0];
        b[1] = w1r[kb][1];
      } else {
#pragma unroll
        for (int nf = 0; nf < 2; nf++)
          b[nf] = W1F[((kb - 4) * 8 + wc * 2 + nf) * 64 + lane];
      }
#pragma unroll
      for (int mf = 0; mf < 2; mf++)
#pragma unroll
        for (int nf = 0; nf < 2; nf++)
          acc[mf][nf] = __builtin_amdgcn_mfma_f32_16x16x32_bf16(a[mf], b[nf], acc[mf][nf], 0, 0, 0);
    }
    __syncthreads();  // all waves done reading A(t)

    // ---- phase: x1-write(t) + A-write(t+1) + issue gathers(t+2) ----
#pragma unroll
    for (int nf = 0; nf < 2; nf++) {
      const int col = wc * 32 + nf * 16 + lq;
      const float s1v = SC[col], c1v = SC[128 + col];
#pragma unroll
      for (int mf = 0; mf < 2; mf++) {
#pragma unroll
        for (int j = 0; j < 4; j++) {
          int row = wr * 32 + mf * 16 + 4 * g + j;
          float v = fmaxf(acc[mf][nf][j] * s1v + c1v, 0.f);
          *(unsigned short*)(X1 + row * 256 + ((col * 2) ^ ((row & 7) << 4))) = f2bf(v);
        }
      }
    }
    writeA();  // tile t+1 (regs), last tile rewrites same data harmlessly
    {
      int tn2 = t + 2 * grid;
      if (tn2 >= nblk) tn2 = t + grid < nblk ? t + grid : t;
      gatherNext(tn2);
    }
    __syncthreads();  // x1(t) + A(t+1) visible

    // ---- layer 2: x1[128x128] @ W2[128x64]; 1x2 frags per wave, W2 from regs ----
    f32x4 acc2[2];
#pragma unroll
    for (int nf = 0; nf < 2; nf++) {
      f32x4 zv = {0.f, 0.f, 0.f, 0.f};
      acc2[nf] = zv;
    }
#pragma unroll
    for (int kb = 0; kb < 4; kb++) {
      int row = w2r * 16 + lq;
      bf16x8 a2 = *(const bf16x8*)(X1 + row * 256 + ((kb * 64 + g * 16) ^ ((row & 7) << 4)));
#pragma unroll
      for (int nf = 0; nf < 2; nf++)
        acc2[nf] = __builtin_amdgcn_mfma_f32_16x16x32_bf16(a2, w2g[kb][nf], acc2[nf], 0, 0, 0);
    }

    // ---- layer 3: bn+relu, dot w3, 16-lane shfl reduce ----
    const int colA = w2c * 32 + lq, colB = colA + 16;
    const float s2A = SC[256 + colA], c2A = SC[320 + colA];
    const float s2B = SC[256 + colB], c2B = SC[320 + colB];
    const float w3A = SC[384 + colA], w3B = SC[384 + colB];
#pragma unroll
    for (int j = 0; j < 4; j++) {
      float vA = fmaxf(acc2[0][j] * s2A + c2A, 0.f);
      float vB = fmaxf(acc2[1][j] * s2B + c2B, 0.f);
      float p = vA * w3A + vB * w3B;
      p += __shfl_xor(p, 1);
      p += __shfl_xor(p, 2);
      p += __shfl_xor(p, 4);
      p += __shfl_xor(p, 8);
      if (lq == 0) l3[(w2r * 16 + 4 * g + j) * 2 + w2c] = p;
    }
    __syncthreads();  // l3 visible

    // ---- out(t); next L1(t+1) follows immediately (A(t+1) already visible) ----
    if (tid < 128) {
      int e = (t << 7) + tid;
      if (e < E) out[e] = l3[tid * 2] + l3[tid * 2 + 1] + SC[448];
    }
  }
}

extern "C" void kernel_launch(void* const* d_in, const int* in_sizes, int n_in,
                              void* d_out, int out_size, void* d_ws, size_t ws_size,
                              hipStream_t stream) {
  const float* z = (const float*)d_in[0];
  const int* ei = (const int*)d_in[1];
  const float* ctx = (const float*)d_in[2];
  const float* W1 = (const float*)d_in[3];
  const float* b1 = (const float*)d_in[4];
  const float* g1 = (const float*)d_in[5];
  const float* be1 = (const float*)d_in[6];
  const float* m1 = (const float*)d_in[7];
  const float* v1 = (const float*)d_in[8];
  const float* W2 = (const float*)d_in[9];
  const float* b2 = (const float*)d_in[10];
  const float* g2 = (const float*)d_in[11];
  const float* be2 = (const float*)d_in[12];
  const float* m2 = (const float*)d_in[13];
  const float* v2 = (const float*)d_in[14];
  const float* W3 = (const float*)d_in[15];
  const float* b3 = (const float*)d_in[16];
  float* out = (float*)d_out;
  const int E = out_size;

  unsigned short* w1f = (unsigned short*)d_ws;
  unsigned short* w2f = (unsigned short*)((char*)d_ws + 73728);
  float* sc = (float*)((char*)d_ws + 90112);

  prep_kernel<<<177, 256, 0, stream>>>(W1, W2, b1, g1, be1, m1, v1,
                                       b2, g2, be2, m2, v2, w1f, w2f, sc);

  const int nblk = (E + 127) >> 7;
  (void)hipFuncSetAttribute((const void*)fused_kernel,
                            hipFuncAttributeMaxDynamicSharedMemorySize, LDS_TOTAL);
  fused_kernel<<<256, 1024, LDS_TOTAL, stream>>>(z, ei, ctx, w1f, w2f, sc, W3, b3,
                                                 out, E, nblk);
}

// Round 4
// 329.325 us; speedup vs baseline: 1.2566x; 1.2566x over previous
//
#include <hip/hip_runtime.h>
#include <hip/hip_bf16.h>

typedef __attribute__((ext_vector_type(8))) short bf16x8;
typedef __attribute__((ext_vector_type(4))) float f32x4;
typedef __attribute__((ext_vector_type(4))) unsigned int u32x4;
typedef __attribute__((ext_vector_type(2))) unsigned int u32x2;

#define EPS 1e-5f

__device__ inline unsigned short f2bf(float x) {
  unsigned int u = __builtin_bit_cast(unsigned int, x);
  unsigned int r = (u + 0x7FFFu + ((u >> 16) & 1u)) >> 16;
  return (unsigned short)r;
}

__device__ inline unsigned int pk2(float a, float b) {
  return (unsigned int)f2bf(a) | ((unsigned int)f2bf(b) << 16);
}

// ---------------- prep: fold BN, pre-swizzle W1/W2 into MFMA fragment order ----------------
// ws layout: w1f bf16 [73728 B] | w2f bf16 [16384 B] | sc f32[384]
__global__ void prep_kernel(const float* __restrict__ W1, const float* __restrict__ W2,
                            const float* __restrict__ b1, const float* __restrict__ g1,
                            const float* __restrict__ be1, const float* __restrict__ m1,
                            const float* __restrict__ v1,
                            const float* __restrict__ b2, const float* __restrict__ g2,
                            const float* __restrict__ be2, const float* __restrict__ m2,
                            const float* __restrict__ v2,
                            unsigned short* __restrict__ w1f, unsigned short* __restrict__ w2f,
                            float* __restrict__ sc) {
  int t = blockIdx.x * 256 + threadIdx.x;
  if (t < 36864) {
    int j = t & 7, l = (t >> 3) & 63, f = t >> 9;
    int kb = f >> 3, nb = f & 7;
    int rk = kb * 32 + ((l >> 4) << 3) + j;
    int cn = (nb << 4) + (l & 15);
    w1f[t] = f2bf(W1[rk * 128 + cn]);
  } else if (t < 45056) {
    int o = t - 36864;
    int j = o & 7, l = (o >> 3) & 63, f = o >> 9;
    int kb = f >> 2, nb = f & 3;
    int rk = kb * 32 + ((l >> 4) << 3) + j;
    int cn = (nb << 4) + (l & 15);
    w2f[o] = f2bf(W2[rk * 64 + cn]);
  } else if (t < 45184) {
    int j = t - 45056;
    float s = g1[j] * rsqrtf(v1[j] + EPS);
    sc[j] = s;
    sc[128 + j] = (b1[j] - m1[j]) * s + be1[j];
  } else if (t < 45248) {
    int j = t - 45184;
    float s = g2[j] * rsqrtf(v2[j] + EPS);
    sc[256 + j] = s;
    sc[320 + j] = (b2[j] - m2[j]) * s + be2[j];
  }
}

// ---------------- fused main kernel (1024 threads = 16 waves) ----------------
// LDS map:
//   [0, 40960)        W1 frags kb4..8 (kb0..3 live in registers)
//   [40960, 43008)    SC (s1,c1,s2,c2,w3,b3)
//   [43008, 124928)   A-tile [128 rows x 640 B], XOR-swizzled
//   [124928, 157696)  x1 [128 rows x 256 B], XOR-swizzled
//   [157696, 158720)  l3 f32[256]
#define LDS_SC_OFF 40960
#define LDS_A_OFF 43008
#define LDS_X1_OFF 124928
#define LDS_L3_OFF 157696
#define LDS_TOTAL 158720

// macros (NOT lambdas — reference-captured lambdas forced locals to scratch in R3:
// WRITE_SIZE 3.9->49 MB, FETCH 286->971 MB, 2.5x dur regression)
#define WRITE_A()                                                                                \
  do {                                                                                           \
    const int rswz_ = (sr & 7) << 4;                                                             \
    char* rowp_ = AR + sr * 640;                                                                 \
    u32x4 ps_ = {pk2(sv0[0], sv0[1]), pk2(sv0[2], sv0[3]), pk2(sv1[0], sv1[1]),                  \
                 pk2(sv1[2], sv1[3])};                                                           \
    u32x4 pd_ = {pk2(dv0[0], dv0[1]), pk2(dv0[2], dv0[3]), pk2(dv1[0], dv1[1]),                  \
                 pk2(dv1[2], dv1[3])};                                                           \
    u32x4 pp_ = {pk2(sv0[0] * dv0[0], sv0[1] * dv0[1]), pk2(sv0[2] * dv0[2], sv0[3] * dv0[3]),   \
                 pk2(sv1[0] * dv1[0], sv1[1] * dv1[1]), pk2(sv1[2] * dv1[2], sv1[3] * dv1[3])};  \
    u32x4 pa_ = {pk2(fabsf(sv0[0] - dv0[0]), fabsf(sv0[1] - dv0[1])),                            \
                 pk2(fabsf(sv0[2] - dv0[2]), fabsf(sv0[3] - dv0[3])),                            \
                 pk2(fabsf(sv1[0] - dv1[0]), fabsf(sv1[1] - dv1[1])),                            \
                 pk2(fabsf(sv1[2] - dv1[2]), fabsf(sv1[3] - dv1[3]))};                           \
    u32x2 pc_ = {pk2(cv[0], cv[1]), pk2(cv[2], cv[3])};                                          \
    *(u32x4*)(rowp_ + ((sh * 16) ^ rswz_)) = ps_;                                                \
    *(u32x4*)(rowp_ + ((128 + sh * 16) ^ rswz_)) = pd_;                                          \
    *(u32x4*)(rowp_ + ((256 + sh * 16) ^ rswz_)) = pp_;                                          \
    *(u32x4*)(rowp_ + ((384 + sh * 16) ^ rswz_)) = pa_;                                          \
    *(u32x2*)(rowp_ + 512 + ((sh * 8) ^ rswz_)) = pc_;                                           \
  } while (0)

#define GATHER_NEXT(tg)                                                                          \
  do {                                                                                           \
    const f32x4* zs_ = (const f32x4*)(z + ((size_t)i0n * 64 + sh * 8));                          \
    sv0 = zs_[0];                                                                                \
    sv1 = zs_[1];                                                                                \
    const f32x4* zd_ = (const f32x4*)(z + ((size_t)i1n * 64 + sh * 8));                          \
    dv0 = zd_[0];                                                                                \
    dv1 = zd_[1];                                                                                \
    int eg_ = ((tg) << 7) + sr;                                                                  \
    int esg_ = eg_ < E ? eg_ : E - 1;                                                            \
    cv = *(const f32x4*)(ctx + (size_t)esg_ * 32 + sh * 4);                                      \
    int tn_ = (tg) + grid;                                                                       \
    if (tn_ >= nblk) tn_ = (tg);                                                                 \
    int en_ = (tn_ << 7) + sr;                                                                   \
    int esn_ = en_ < E ? en_ : E - 1;                                                            \
    i0n = ei[esn_];                                                                              \
    i1n = ei[E + esn_];                                                                          \
  } while (0)

__global__ __launch_bounds__(1024, 1) void fused_kernel(
    const float* __restrict__ z, const int* __restrict__ ei, const float* __restrict__ ctx,
    const unsigned short* __restrict__ w1f, const unsigned short* __restrict__ w2f,
    const float* __restrict__ sc, const float* __restrict__ w3, const float* __restrict__ b3,
    float* __restrict__ out, int E, int nblk) {
  extern __shared__ char lds[];
  char* W1L = lds;
  float* SC = (float*)(lds + LDS_SC_OFF);
  char* AR = lds + LDS_A_OFF;
  char* X1 = lds + LDS_X1_OFF;
  float* l3 = (float*)(lds + LDS_L3_OFF);

  const int tid = threadIdx.x;
  const int lane = tid & 63, wave = tid >> 6;
  const int g = lane >> 4, lq = lane & 15;
  const int wr = wave >> 2, wc = wave & 3;   // L1 grid 4x4: 32 rows x 32 cols per wave
  const int w2r = wave >> 1, w2c = wave & 1; // L2 grid 8x2: 16 rows x 32 cols per wave
  const int sr = tid >> 3, sh = tid & 7;     // staging: 8 threads per edge
  const int grid = gridDim.x;

  // ---- stage W1 kb4..8 (40 KB) + SC into LDS ----
  {
    const f32x4* s = (const f32x4*)(w1f + 16384);
    f32x4* d = (f32x4*)W1L;
    d[tid] = s[tid];
    d[1024 + tid] = s[1024 + tid];
    if (tid < 512) d[2048 + tid] = s[2048 + tid];
    if (tid < 128) {
      SC[tid] = sc[tid];
      SC[128 + tid] = sc[128 + tid];
    } else if (tid < 192) {
      int j = tid - 128;
      SC[256 + j] = sc[256 + j];
      SC[320 + j] = sc[320 + j];
      SC[384 + j] = w3[j];
    } else if (tid == 192) {
      SC[448] = b3[0];
    }
  }

  // ---- persistent W fragments in registers ----
  bf16x8 w1r0, w1r1, w1r2, w1r3, w1s0, w1s1, w1s2, w1s3;
  bf16x8 w2g0, w2g1, w2g2, w2g3, w2h0, w2h1, w2h2, w2h3;
  {
    const bf16x8* W1G = (const bf16x8*)w1f;
    const bf16x8* W2G = (const bf16x8*)w2f;
    w1r0 = W1G[(0 * 8 + wc * 2 + 0) * 64 + lane];
    w1s0 = W1G[(0 * 8 + wc * 2 + 1) * 64 + lane];
    w1r1 = W1G[(1 * 8 + wc * 2 + 0) * 64 + lane];
    w1s1 = W1G[(1 * 8 + wc * 2 + 1) * 64 + lane];
    w1r2 = W1G[(2 * 8 + wc * 2 + 0) * 64 + lane];
    w1s2 = W1G[(2 * 8 + wc * 2 + 1) * 64 + lane];
    w1r3 = W1G[(3 * 8 + wc * 2 + 0) * 64 + lane];
    w1s3 = W1G[(3 * 8 + wc * 2 + 1) * 64 + lane];
    w2g0 = W2G[(0 * 4 + w2c * 2 + 0) * 64 + lane];
    w2h0 = W2G[(0 * 4 + w2c * 2 + 1) * 64 + lane];
    w2g1 = W2G[(1 * 4 + w2c * 2 + 0) * 64 + lane];
    w2h1 = W2G[(1 * 4 + w2c * 2 + 1) * 64 + lane];
    w2g2 = W2G[(2 * 4 + w2c * 2 + 0) * 64 + lane];
    w2h2 = W2G[(2 * 4 + w2c * 2 + 1) * 64 + lane];
    w2g3 = W2G[(3 * 4 + w2c * 2 + 0) * 64 + lane];
    w2h3 = W2G[(3 * 4 + w2c * 2 + 1) * 64 + lane];
  }

  f32x4 sv0, sv1, dv0, dv1, cv;
  int i0n, i1n;
  int t = blockIdx.x;

  // ---- prologue: gather tile t, write A(t), gather t+1, prefetch ei t+2 ----
  {
    int e = (t << 7) + sr;
    int es = e < E ? e : E - 1;
    int a0 = ei[es], a1 = ei[E + es];
    cv = *(const f32x4*)(ctx + (size_t)es * 32 + sh * 4);
    const f32x4* zs = (const f32x4*)(z + ((size_t)a0 * 64 + sh * 8));
    sv0 = zs[0];
    sv1 = zs[1];
    const f32x4* zd = (const f32x4*)(z + ((size_t)a1 * 64 + sh * 8));
    dv0 = zd[0];
    dv1 = zd[1];
    int tn = t + grid;
    if (tn >= nblk) tn = t;
    int en = (tn << 7) + sr;
    int esn = en < E ? en : E - 1;
    i0n = ei[esn];
    i1n = ei[E + esn];
  }
  WRITE_A();
  {
    int tn = t + grid;
    if (tn >= nblk) tn = t;
    GATHER_NEXT(tn);
  }
  __syncthreads();  // A(t) + W1L + SC visible

  for (; t < nblk; t += grid) {
    // ---- layer 1: A[128x288] @ W1[288x128]; 2x2 16x16 frags per wave ----
    f32x4 acc00 = {0.f, 0.f, 0.f, 0.f}, acc01 = acc00, acc10 = acc00, acc11 = acc00;
    const bf16x8* W1F = (const bf16x8*)W1L;
    const int row0 = wr * 32 + lq, row1 = row0 + 16;
    const int swz0 = (row0 & 7) << 4, swz1 = (row1 & 7) << 4;
    const char* ap0 = AR + row0 * 640;
    const char* ap1 = AR + row1 * 640;
#pragma unroll
    for (int kb = 0; kb < 9; kb++) {
      bf16x8 a0 = *(const bf16x8*)(ap0 + ((kb * 64 + g * 16) ^ swz0));
      bf16x8 a1 = *(const bf16x8*)(ap1 + ((kb * 64 + g * 16) ^ swz1));
      bf16x8 b0, b1;
      if (kb == 0) { b0 = w1r0; b1 = w1s0; }
      else if (kb == 1) { b0 = w1r1; b1 = w1s1; }
      else if (kb == 2) { b0 = w1r2; b1 = w1s2; }
      else if (kb == 3) { b0 = w1r3; b1 = w1s3; }
      else {
        b0 = W1F[((kb - 4) * 8 + wc * 2 + 0) * 64 + lane];
        b1 = W1F[((kb - 4) * 8 + wc * 2 + 1) * 64 + lane];
      }
      acc00 = __builtin_amdgcn_mfma_f32_16x16x32_bf16(a0, b0, acc00, 0, 0, 0);
      acc01 = __builtin_amdgcn_mfma_f32_16x16x32_bf16(a0, b1, acc01, 0, 0, 0);
      acc10 = __builtin_amdgcn_mfma_f32_16x16x32_bf16(a1, b0, acc10, 0, 0, 0);
      acc11 = __builtin_amdgcn_mfma_f32_16x16x32_bf16(a1, b1, acc11, 0, 0, 0);
    }
    __syncthreads();  // all waves done reading A(t)

    // ---- phase: A-write(t+1), issue gathers(t+2), x1-write(t) ----
    WRITE_A();  // consumes sv/dv/cv regs for t+1
    {
      int tn2 = t + 2 * grid;
      if (tn2 >= nblk) tn2 = t + grid < nblk ? t + grid : t;
      GATHER_NEXT(tn2);  // long-latency loads issue here, hide under x1-write VALU
    }
#pragma unroll
    for (int nf = 0; nf < 2; nf++) {
      const int col = wc * 32 + nf * 16 + lq;
      const float s1v = SC[col], c1v = SC[128 + col];
      const f32x4 aA = nf ? acc01 : acc00;
      const f32x4 aB = nf ? acc11 : acc10;
#pragma unroll
      for (int j = 0; j < 4; j++) {
        int rowa = wr * 32 + 4 * g + j;
        float v = fmaxf(aA[j] * s1v + c1v, 0.f);
        *(unsigned short*)(X1 + rowa * 256 + ((col * 2) ^ ((rowa & 7) << 4))) = f2bf(v);
        int rowb = rowa + 16;
        float w = fmaxf(aB[j] * s1v + c1v, 0.f);
        *(unsigned short*)(X1 + rowb * 256 + ((col * 2) ^ ((rowb & 7) << 4))) = f2bf(w);
      }
    }
    __syncthreads();  // x1(t) + A(t+1) visible

    // ---- layer 2: x1[128x128] @ W2[128x64]; 1x2 frags per wave, W2 from regs ----
    f32x4 acc2A = {0.f, 0.f, 0.f, 0.f}, acc2B = acc2A;
    {
      const int row = w2r * 16 + lq;
      const int swz = (row & 7) << 4;
      const char* xp = X1 + row * 256;
      bf16x8 a0 = *(const bf16x8*)(xp + ((0 * 64 + g * 16) ^ swz));
      acc2A = __builtin_amdgcn_mfma_f32_16x16x32_bf16(a0, w2g0, acc2A, 0, 0, 0);
      acc2B = __builtin_amdgcn_mfma_f32_16x16x32_bf16(a0, w2h0, acc2B, 0, 0, 0);
      bf16x8 a1 = *(const bf16x8*)(xp + ((1 * 64 + g * 16) ^ swz));
      acc2A = __builtin_amdgcn_mfma_f32_16x16x32_bf16(a1, w2g1, acc2A, 0, 0, 0);
      acc2B = __builtin_amdgcn_mfma_f32_16x16x32_bf16(a1, w2h1, acc2B, 0, 0, 0);
      bf16x8 a2 = *(const bf16x8*)(xp + ((2 * 64 + g * 16) ^ swz));
      acc2A = __builtin_amdgcn_mfma_f32_16x16x32_bf16(a2, w2g2, acc2A, 0, 0, 0);
      acc2B = __builtin_amdgcn_mfma_f32_16x16x32_bf16(a2, w2h2, acc2B, 0, 0, 0);
      bf16x8 a3 = *(const bf16x8*)(xp + ((3 * 64 + g * 16) ^ swz));
      acc2A = __builtin_amdgcn_mfma_f32_16x16x32_bf16(a3, w2g3, acc2A, 0, 0, 0);
      acc2B = __builtin_amdgcn_mfma_f32_16x16x32_bf16(a3, w2h3, acc2B, 0, 0, 0);
    }

    // ---- layer 3: bn+relu, dot w3, 16-lane shfl reduce ----
    const int colA = w2c * 32 + lq, colB = colA + 16;
    const float s2A = SC[256 + colA], c2A = SC[320 + colA];
    const float s2B = SC[256 + colB], c2B = SC[320 + colB];
    const float w3A = SC[384 + colA], w3B = SC[384 + colB];
#pragma unroll
    for (int j = 0; j < 4; j++) {
      float vA = fmaxf(acc2A[j] * s2A + c2A, 0.f);
      float vB = fmaxf(acc2B[j] * s2B + c2B, 0.f);
      float p = vA * w3A + vB * w3B;
      p += __shfl_xor(p, 1);
      p += __shfl_xor(p, 2);
      p += __shfl_xor(p, 4);
      p += __shfl_xor(p, 8);
      if (lq == 0) l3[(w2r * 16 + 4 * g + j) * 2 + w2c] = p;
    }
    __syncthreads();  // l3 visible

    // ---- out(t); next L1(t+1) follows immediately (A(t+1) already visible) ----
    if (tid < 128) {
      int e = (t << 7) + tid;
      if (e < E) out[e] = l3[tid * 2] + l3[tid * 2 + 1] + SC[448];
    }
  }
}

extern "C" void kernel_launch(void* const* d_in, const int* in_sizes, int n_in,
                              void* d_out, int out_size, void* d_ws, size_t ws_size,
                              hipStream_t stream) {
  const float* z = (const float*)d_in[0];
  const int* ei = (const int*)d_in[1];
  const float* ctx = (const float*)d_in[2];
  const float* W1 = (const float*)d_in[3];
  const float* b1 = (const float*)d_in[4];
  const float* g1 = (const float*)d_in[5];
  const float* be1 = (const float*)d_in[6];
  const float* m1 = (const float*)d_in[7];
  const float* v1 = (const float*)d_in[8];
  const float* W2 = (const float*)d_in[9];
  const float* b2 = (const float*)d_in[10];
  const float* g2 = (const float*)d_in[11];
  const float* be2 = (const float*)d_in[12];
  const float* m2 = (const float*)d_in[13];
  const float* v2 = (const float*)d_in[14];
  const float* W3 = (const float*)d_in[15];
  const float* b3 = (const float*)d_in[16];
  float* out = (float*)d_out;
  const int E = out_size;

  unsigned short* w1f = (unsigned short*)d_ws;
  unsigned short* w2f = (unsigned short*)((char*)d_ws + 73728);
  float* sc = (float*)((char*)d_ws + 90112);

  prep_kernel<<<177, 256, 0, stream>>>(W1, W2, b1, g1, be1, m1, v1,
                                       b2, g2, be2, m2, v2, w1f, w2f, sc);

  const int nblk = (E + 127) >> 7;
  (void)hipFuncSetAttribute((const void*)fused_kernel,
                            hipFuncAttributeMaxDynamicSharedMemorySize, LDS_TOTAL);
  fused_kernel<<<256, 1024, LDS_TOTAL, stream>>>(z, ei, ctx, w1f, w2f, sc, W3, b3,
                                                 out, E, nblk);
}

// Round 5
// 158.385 us; speedup vs baseline: 2.6128x; 2.0793x over previous
//
#include <hip/hip_runtime.h>
#include <hip/hip_bf16.h>

typedef __attribute__((ext_vector_type(8))) short bf16x8;
typedef __attribute__((ext_vector_type(4))) float f32x4;
typedef __attribute__((ext_vector_type(4))) unsigned int u32x4;
typedef __attribute__((ext_vector_type(2))) unsigned int u32x2;

#define EPS 1e-5f

__device__ inline unsigned short f2bf(float x) {  // RNE (prep kernel only; cold)
  unsigned int u = __builtin_bit_cast(unsigned int, x);
  unsigned int r = (u + 0x7FFFu + ((u >> 16) & 1u)) >> 16;
  return (unsigned short)r;
}

// hot-path pair pack: round-to-nearest (ties away), 5 VALU ops/pair
__device__ inline unsigned int pkrn(float a, float b) {
  unsigned int ua = __builtin_bit_cast(unsigned int, a) + 0x8000u;
  unsigned int ub = __builtin_bit_cast(unsigned int, b) + 0x8000u;
  return (ua >> 16) | (ub & 0xFFFF0000u);
}
// hot-path single pack: 2 VALU ops
__device__ inline unsigned short bfrn(float x) {
  return (unsigned short)((__builtin_bit_cast(unsigned int, x) + 0x8000u) >> 16);
}

// ---------------- prep: fold BN, pre-swizzle W1/W2 into MFMA fragment order ----------------
// ws layout: w1f bf16 [73728 B] | w2f bf16 [16384 B] | sc f32[384]
__global__ void prep_kernel(const float* __restrict__ W1, const float* __restrict__ W2,
                            const float* __restrict__ b1, const float* __restrict__ g1,
                            const float* __restrict__ be1, const float* __restrict__ m1,
                            const float* __restrict__ v1,
                            const float* __restrict__ b2, const float* __restrict__ g2,
                            const float* __restrict__ be2, const float* __restrict__ m2,
                            const float* __restrict__ v2,
                            unsigned short* __restrict__ w1f, unsigned short* __restrict__ w2f,
                            float* __restrict__ sc) {
  int t = blockIdx.x * 256 + threadIdx.x;
  if (t < 36864) {
    int j = t & 7, l = (t >> 3) & 63, f = t >> 9;
    int kb = f >> 3, nb = f & 7;
    int rk = kb * 32 + ((l >> 4) << 3) + j;
    int cn = (nb << 4) + (l & 15);
    w1f[t] = f2bf(W1[rk * 128 + cn]);
  } else if (t < 45056) {
    int o = t - 36864;
    int j = o & 7, l = (o >> 3) & 63, f = o >> 9;
    int kb = f >> 2, nb = f & 3;
    int rk = kb * 32 + ((l >> 4) << 3) + j;
    int cn = (nb << 4) + (l & 15);
    w2f[o] = f2bf(W2[rk * 64 + cn]);
  } else if (t < 45184) {
    int j = t - 45056;
    float s = g1[j] * rsqrtf(v1[j] + EPS);
    sc[j] = s;
    sc[128 + j] = (b1[j] - m1[j]) * s + be1[j];
  } else if (t < 45248) {
    int j = t - 45184;
    float s = g2[j] * rsqrtf(v2[j] + EPS);
    sc[256 + j] = s;
    sc[320 + j] = (b2[j] - m2[j]) * s + be2[j];
  }
}

// ---------------- fused main kernel (1024 threads = 16 waves) ----------------
// LDS map:
//   [0, 73728)        W1 frags, all 9 kb (persistent)
//   [73728, 75776)    SC (s1,c1,s2,c2,w3,b3)
//   [75776, 157696)   A-tile [128 rows x 640 B], XOR-swizzled
//                     X1 aliases [75776, 108544) (128 rows x 256 B) after L1
//   [157696, 158720)  l3 f32[256]
// W2 frags live in registers (32 VGPR) — W1+W2 both in regs exceeded the
// 128-reg/wave cap of 1024-thr blocks and spilled (R3/R4: 45 MB scratch).
#define LDS_SC_OFF 73728
#define LDS_A_OFF 75776
#define LDS_L3_OFF 157696
#define LDS_TOTAL 158720

#define WRITE_A()                                                                                \
  do {                                                                                           \
    const int rswz_ = (sr & 7) << 4;                                                             \
    char* rowp_ = AR + sr * 640;                                                                 \
    u32x4 ps_ = {pkrn(sv0[0], sv0[1]), pkrn(sv0[2], sv0[3]), pkrn(sv1[0], sv1[1]),               \
                 pkrn(sv1[2], sv1[3])};                                                          \
    u32x4 pd_ = {pkrn(dv0[0], dv0[1]), pkrn(dv0[2], dv0[3]), pkrn(dv1[0], dv1[1]),               \
                 pkrn(dv1[2], dv1[3])};                                                          \
    u32x4 pp_ = {pkrn(sv0[0] * dv0[0], sv0[1] * dv0[1]), pkrn(sv0[2] * dv0[2], sv0[3] * dv0[3]), \
                 pkrn(sv1[0] * dv1[0], sv1[1] * dv1[1]), pkrn(sv1[2] * dv1[2], sv1[3] * dv1[3])};\
    u32x4 pa_ = {pkrn(fabsf(sv0[0] - dv0[0]), fabsf(sv0[1] - dv0[1])),                           \
                 pkrn(fabsf(sv0[2] - dv0[2]), fabsf(sv0[3] - dv0[3])),                           \
                 pkrn(fabsf(sv1[0] - dv1[0]), fabsf(sv1[1] - dv1[1])),                           \
                 pkrn(fabsf(sv1[2] - dv1[2]), fabsf(sv1[3] - dv1[3]))};                          \
    u32x2 pc_ = {pkrn(cv[0], cv[1]), pkrn(cv[2], cv[3])};                                        \
    *(u32x4*)(rowp_ + ((sh * 16) ^ rswz_)) = ps_;                                                \
    *(u32x4*)(rowp_ + ((128 + sh * 16) ^ rswz_)) = pd_;                                          \
    *(u32x4*)(rowp_ + ((256 + sh * 16) ^ rswz_)) = pp_;                                          \
    *(u32x4*)(rowp_ + ((384 + sh * 16) ^ rswz_)) = pa_;                                          \
    *(u32x2*)(rowp_ + 512 + ((sh * 8) ^ rswz_)) = pc_;                                           \
  } while (0)

#define GATHER_NEXT(tg)                                                                          \
  do {                                                                                           \
    const f32x4* zs_ = (const f32x4*)(z + ((size_t)i0n * 64 + sh * 8));                          \
    sv0 = zs_[0];                                                                                \
    sv1 = zs_[1];                                                                                \
    const f32x4* zd_ = (const f32x4*)(z + ((size_t)i1n * 64 + sh * 8));                          \
    dv0 = zd_[0];                                                                                \
    dv1 = zd_[1];                                                                                \
    int eg_ = ((tg) << 7) + sr;                                                                  \
    int esg_ = eg_ < E ? eg_ : E - 1;                                                            \
    cv = *(const f32x4*)(ctx + (size_t)esg_ * 32 + sh * 4);                                      \
    int tn_ = (tg) + grid;                                                                       \
    if (tn_ >= nblk) tn_ = (tg);                                                                 \
    int en_ = (tn_ << 7) + sr;                                                                   \
    int esn_ = en_ < E ? en_ : E - 1;                                                            \
    i0n = ei[esn_];                                                                              \
    i1n = ei[E + esn_];                                                                          \
  } while (0)

__global__ __launch_bounds__(1024, 4) void fused_kernel(
    const float* __restrict__ z, const int* __restrict__ ei, const float* __restrict__ ctx,
    const unsigned short* __restrict__ w1f, const unsigned short* __restrict__ w2f,
    const float* __restrict__ sc, const float* __restrict__ w3, const float* __restrict__ b3,
    float* __restrict__ out, int E, int nblk) {
  extern __shared__ char lds[];
  char* W1L = lds;
  float* SC = (float*)(lds + LDS_SC_OFF);
  char* AR = lds + LDS_A_OFF;
  char* X1 = lds + LDS_A_OFF;  // alias: x1 overwrites A-head after L1 reads complete
  float* l3 = (float*)(lds + LDS_L3_OFF);

  const int tid = threadIdx.x;
  const int lane = tid & 63, wave = tid >> 6;
  const int g = lane >> 4, lq = lane & 15;
  const int wr = wave >> 2, wc = wave & 3;   // L1 grid 4x4: 32 rows x 32 cols per wave
  const int w2r = wave >> 1, w2c = wave & 1; // L2 grid 8x2: 16 rows x 32 cols per wave
  const int sr = tid >> 3, sh = tid & 7;     // staging: 8 threads per edge
  const int grid = gridDim.x;

  // ---- stage W1 (72 KB) + SC into LDS ----
  {
    const f32x4* s = (const f32x4*)w1f;
    f32x4* d = (f32x4*)W1L;
#pragma unroll
    for (int i = 0; i < 4; i++) d[i * 1024 + tid] = s[i * 1024 + tid];
    if (tid < 512) d[4096 + tid] = s[4096 + tid];
    if (tid < 128) {
      SC[tid] = sc[tid];
      SC[128 + tid] = sc[128 + tid];
    } else if (tid < 192) {
      int j = tid - 128;
      SC[256 + j] = sc[256 + j];
      SC[320 + j] = sc[320 + j];
      SC[384 + j] = w3[j];
    } else if (tid == 192) {
      SC[448] = b3[0];
    }
  }

  // ---- persistent W2 fragments in registers (32 VGPR) ----
  bf16x8 w2g0, w2g1, w2g2, w2g3, w2h0, w2h1, w2h2, w2h3;
  {
    const bf16x8* W2G = (const bf16x8*)w2f;
    w2g0 = W2G[(0 * 4 + w2c * 2 + 0) * 64 + lane];
    w2h0 = W2G[(0 * 4 + w2c * 2 + 1) * 64 + lane];
    w2g1 = W2G[(1 * 4 + w2c * 2 + 0) * 64 + lane];
    w2h1 = W2G[(1 * 4 + w2c * 2 + 1) * 64 + lane];
    w2g2 = W2G[(2 * 4 + w2c * 2 + 0) * 64 + lane];
    w2h2 = W2G[(2 * 4 + w2c * 2 + 1) * 64 + lane];
    w2g3 = W2G[(3 * 4 + w2c * 2 + 0) * 64 + lane];
    w2h3 = W2G[(3 * 4 + w2c * 2 + 1) * 64 + lane];
  }

  f32x4 sv0, sv1, dv0, dv1, cv;
  int i0n, i1n;
  int t = blockIdx.x;

  // ---- prologue: gather tile t, write A(t), gather t+1, prefetch ei t+2 ----
  {
    int e = (t << 7) + sr;
    int es = e < E ? e : E - 1;
    int a0 = ei[es], a1 = ei[E + es];
    cv = *(const f32x4*)(ctx + (size_t)es * 32 + sh * 4);
    const f32x4* zs = (const f32x4*)(z + ((size_t)a0 * 64 + sh * 8));
    sv0 = zs[0];
    sv1 = zs[1];
    const f32x4* zd = (const f32x4*)(z + ((size_t)a1 * 64 + sh * 8));
    dv0 = zd[0];
    dv1 = zd[1];
    int tn = t + grid;
    if (tn >= nblk) tn = t;
    int en = (tn << 7) + sr;
    int esn = en < E ? en : E - 1;
    i0n = ei[esn];
    i1n = ei[E + esn];
  }
  WRITE_A();
  {
    int tn = t + grid;
    if (tn >= nblk) tn = t;
    GATHER_NEXT(tn);
  }
  __syncthreads();  // A(t) + W1L + SC visible

  for (; t < nblk; t += grid) {
    // ---- layer 1: A[128x288] @ W1[288x128]; 2x2 16x16 frags per wave ----
    f32x4 acc00 = {0.f, 0.f, 0.f, 0.f}, acc01 = acc00, acc10 = acc00, acc11 = acc00;
    const bf16x8* W1F = (const bf16x8*)W1L;
    const int row0 = wr * 32 + lq, row1 = row0 + 16;
    const int swz0 = (row0 & 7) << 4, swz1 = (row1 & 7) << 4;
    const char* ap0 = AR + row0 * 640;
    const char* ap1 = AR + row1 * 640;
#pragma unroll
    for (int kb = 0; kb < 9; kb++) {
      bf16x8 a0 = *(const bf16x8*)(ap0 + ((kb * 64 + g * 16) ^ swz0));
      bf16x8 a1 = *(const bf16x8*)(ap1 + ((kb * 64 + g * 16) ^ swz1));
      bf16x8 b0 = W1F[(kb * 8 + wc * 2 + 0) * 64 + lane];
      bf16x8 b1 = W1F[(kb * 8 + wc * 2 + 1) * 64 + lane];
      acc00 = __builtin_amdgcn_mfma_f32_16x16x32_bf16(a0, b0, acc00, 0, 0, 0);
      acc01 = __builtin_amdgcn_mfma_f32_16x16x32_bf16(a0, b1, acc01, 0, 0, 0);
      acc10 = __builtin_amdgcn_mfma_f32_16x16x32_bf16(a1, b0, acc10, 0, 0, 0);
      acc11 = __builtin_amdgcn_mfma_f32_16x16x32_bf16(a1, b1, acc11, 0, 0, 0);
    }
    __syncthreads();  // all waves done reading A(t); X1 alias region now writable

    // ---- x1-write(t): bn+relu, bf16, XOR-swizzled ----
#pragma unroll
    for (int nf = 0; nf < 2; nf++) {
      const int col = wc * 32 + nf * 16 + lq;
      const float s1v = SC[col], c1v = SC[128 + col];
      const f32x4 aA = nf ? acc01 : acc00;
      const f32x4 aB = nf ? acc11 : acc10;
#pragma unroll
      for (int j = 0; j < 4; j++) {
        int rowa = wr * 32 + 4 * g + j;
        float v = fmaxf(aA[j] * s1v + c1v, 0.f);
        *(unsigned short*)(X1 + rowa * 256 + ((col * 2) ^ ((rowa & 7) << 4))) = bfrn(v);
        int rowb = rowa + 16;
        float w = fmaxf(aB[j] * s1v + c1v, 0.f);
        *(unsigned short*)(X1 + rowb * 256 + ((col * 2) ^ ((rowb & 7) << 4))) = bfrn(w);
      }
    }
    __syncthreads();  // x1(t) visible

    // ---- layer 2: x1[128x128] @ W2[128x64]; 1x2 frags per wave, W2 from regs ----
    f32x4 acc2A = {0.f, 0.f, 0.f, 0.f}, acc2B = acc2A;
    {
      const int row = w2r * 16 + lq;
      const int swz = (row & 7) << 4;
      const char* xp = X1 + row * 256;
      bf16x8 a0 = *(const bf16x8*)(xp + ((0 * 64 + g * 16) ^ swz));
      acc2A = __builtin_amdgcn_mfma_f32_16x16x32_bf16(a0, w2g0, acc2A, 0, 0, 0);
      acc2B = __builtin_amdgcn_mfma_f32_16x16x32_bf16(a0, w2h0, acc2B, 0, 0, 0);
      bf16x8 a1 = *(const bf16x8*)(xp + ((1 * 64 + g * 16) ^ swz));
      acc2A = __builtin_amdgcn_mfma_f32_16x16x32_bf16(a1, w2g1, acc2A, 0, 0, 0);
      acc2B = __builtin_amdgcn_mfma_f32_16x16x32_bf16(a1, w2h1, acc2B, 0, 0, 0);
      bf16x8 a2 = *(const bf16x8*)(xp + ((2 * 64 + g * 16) ^ swz));
      acc2A = __builtin_amdgcn_mfma_f32_16x16x32_bf16(a2, w2g2, acc2A, 0, 0, 0);
      acc2B = __builtin_amdgcn_mfma_f32_16x16x32_bf16(a2, w2h2, acc2B, 0, 0, 0);
      bf16x8 a3 = *(const bf16x8*)(xp + ((3 * 64 + g * 16) ^ swz));
      acc2A = __builtin_amdgcn_mfma_f32_16x16x32_bf16(a3, w2g3, acc2A, 0, 0, 0);
      acc2B = __builtin_amdgcn_mfma_f32_16x16x32_bf16(a3, w2h3, acc2B, 0, 0, 0);
    }

    // ---- layer 3: bn+relu, dot w3, 16-lane shfl reduce ----
    const int colA = w2c * 32 + lq, colB = colA + 16;
    const float s2A = SC[256 + colA], c2A = SC[320 + colA];
    const float s2B = SC[256 + colB], c2B = SC[320 + colB];
    const float w3A = SC[384 + colA], w3B = SC[384 + colB];
#pragma unroll
    for (int j = 0; j < 4; j++) {
      float vA = fmaxf(acc2A[j] * s2A + c2A, 0.f);
      float vB = fmaxf(acc2B[j] * s2B + c2B, 0.f);
      float p = vA * w3A + vB * w3B;
      p += __shfl_xor(p, 1);
      p += __shfl_xor(p, 2);
      p += __shfl_xor(p, 4);
      p += __shfl_xor(p, 8);
      if (lq == 0) l3[(w2r * 16 + 4 * g + j) * 2 + w2c] = p;
    }
    __syncthreads();  // l3 visible; all x1 reads done -> A region writable

    // ---- phase 4: A-write(t+1) | issue gathers(t+2) | out(t) ----
    WRITE_A();  // consumes t+1 gather regs
    {
      int tn2 = t + 2 * grid;
      if (tn2 >= nblk) tn2 = t + grid < nblk ? t + grid : t;
      GATHER_NEXT(tn2);  // long-latency loads; land during next L1
    }
    if (tid < 128) {
      int e = (t << 7) + tid;
      if (e < E) out[e] = l3[tid * 2] + l3[tid * 2 + 1] + SC[448];
    }
    __syncthreads();  // A(t+1) visible
  }
}

extern "C" void kernel_launch(void* const* d_in, const int* in_sizes, int n_in,
                              void* d_out, int out_size, void* d_ws, size_t ws_size,
                              hipStream_t stream) {
  const float* z = (const float*)d_in[0];
  const int* ei = (const int*)d_in[1];
  const float* ctx = (const float*)d_in[2];
  const float* W1 = (const float*)d_in[3];
  const float* b1 = (const float*)d_in[4];
  const float* g1 = (const float*)d_in[5];
  const float* be1 = (const float*)d_in[6];
  const float* m1 = (const float*)d_in[7];
  const float* v1 = (const float*)d_in[8];
  const float* W2 = (const float*)d_in[9];
  const float* b2 = (const float*)d_in[10];
  const float* g2 = (const float*)d_in[11];
  const float* be2 = (const float*)d_in[12];
  const float* m2 = (const float*)d_in[13];
  const float* v2 = (const float*)d_in[14];
  const float* W3 = (const float*)d_in[15];
  const float* b3 = (const float*)d_in[16];
  float* out = (float*)d_out;
  const int E = out_size;

  unsigned short* w1f = (unsigned short*)d_ws;
  unsigned short* w2f = (unsigned short*)((char*)d_ws + 73728);
  float* sc = (float*)((char*)d_ws + 90112);

  prep_kernel<<<177, 256, 0, stream>>>(W1, W2, b1, g1, be1, m1, v1,
                                       b2, g2, be2, m2, v2, w1f, w2f, sc);

  const int nblk = (E + 127) >> 7;
  (void)hipFuncSetAttribute((const void*)fused_kernel,
                            hipFuncAttributeMaxDynamicSharedMemorySize, LDS_TOTAL);
  fused_kernel<<<256, 1024, LDS_TOTAL, stream>>>(z, ei, ctx, w1f, w2f, sc, W3, b3,
                                                 out, E, nblk);
}

// Round 6
// 137.725 us; speedup vs baseline: 3.0047x; 1.1500x over previous
//
#include <hip/hip_runtime.h>
#include <hip/hip_bf16.h>

typedef __attribute__((ext_vector_type(8))) short bf16x8;
typedef __attribute__((ext_vector_type(4))) float f32x4;
typedef __attribute__((ext_vector_type(4))) unsigned int u32x4;
typedef __attribute__((ext_vector_type(2))) unsigned int u32x2;
typedef __attribute__((ext_vector_type(2))) __bf16 bf16x2v;

#define EPS 1e-5f

__device__ inline unsigned short f2bf(float x) {  // RNE (prep kernel only; cold)
  unsigned int u = __builtin_bit_cast(unsigned int, x);
  unsigned int r = (u + 0x7FFFu + ((u >> 16) & 1u)) >> 16;
  return (unsigned short)r;
}

// hot-path pair pack: compiles to v_cvt_pk_bf16_f32 (1 VALU op; RNE)
__device__ inline unsigned int cvtpk(float a, float b) {
  bf16x2v v = {(__bf16)a, (__bf16)b};
  return __builtin_bit_cast(unsigned int, v);
}

// ---------------- prep: fold BN, pre-swizzle W1/W2 into MFMA fragment order ----------------
// ws layout: w1f bf16 [73728 B] | w2f bf16 [16384 B] | sc f32[384]
// W2 rows are additionally permuted: physical k-slot s holds logical row
// perm(s) = (s&96) | ((s&1)<<4) | ((s>>1)&15)  — matches the packed x1 writes.
__global__ void prep_kernel(const float* __restrict__ W1, const float* __restrict__ W2,
                            const float* __restrict__ b1, const float* __restrict__ g1,
                            const float* __restrict__ be1, const float* __restrict__ m1,
                            const float* __restrict__ v1,
                            const float* __restrict__ b2, const float* __restrict__ g2,
                            const float* __restrict__ be2, const float* __restrict__ m2,
                            const float* __restrict__ v2,
                            unsigned short* __restrict__ w1f, unsigned short* __restrict__ w2f,
                            float* __restrict__ sc) {
  int t = blockIdx.x * 256 + threadIdx.x;
  if (t < 36864) {
    int j = t & 7, l = (t >> 3) & 63, f = t >> 9;
    int kb = f >> 3, nb = f & 7;
    int rk = kb * 32 + ((l >> 4) << 3) + j;
    int cn = (nb << 4) + (l & 15);
    w1f[t] = f2bf(W1[rk * 128 + cn]);
  } else if (t < 45056) {
    int o = t - 36864;
    int j = o & 7, l = (o >> 3) & 63, f = o >> 9;
    int kb = f >> 2, nb = f & 3;
    int s = kb * 32 + ((l >> 4) << 3) + j;          // physical k-slot
    int rk = (s & 96) | ((s & 1) << 4) | ((s >> 1) & 15);  // logical W2 row
    int cn = (nb << 4) + (l & 15);
    w2f[o] = f2bf(W2[rk * 64 + cn]);
  } else if (t < 45184) {
    int j = t - 45056;
    float s = g1[j] * rsqrtf(v1[j] + EPS);
    sc[j] = s;
    sc[128 + j] = (b1[j] - m1[j]) * s + be1[j];
  } else if (t < 45248) {
    int j = t - 45184;
    float s = g2[j] * rsqrtf(v2[j] + EPS);
    sc[256 + j] = s;
    sc[320 + j] = (b2[j] - m2[j]) * s + be2[j];
  }
}

// ---------------- fused main kernel (1024 threads = 16 waves) ----------------
// LDS map:
//   [0, 73728)        W1 frags, all 9 kb (persistent)
//   [73728, 75776)    SC (s1,c1,s2,c2,w3,b3)
//   [75776, 157696)   A-tile [128 rows x 640 B], XOR-swizzled
//                     X1 aliases [75776, 108544) (128 rows x 256 B) after L1
//   [157696, 158720)  l3 f32[256]
// W2 frags live in registers (32 VGPR) — W1+W2 both in regs exceeded the
// 128-reg/wave cap of 1024-thr blocks and spilled (R3/R4: 45 MB scratch).
#define LDS_SC_OFF 73728
#define LDS_A_OFF 75776
#define LDS_L3_OFF 157696
#define LDS_TOTAL 158720

#define WRITE_A()                                                                                \
  do {                                                                                           \
    const int rswz_ = (sr & 7) << 4;                                                             \
    char* rowp_ = AR + sr * 640;                                                                 \
    u32x4 ps_ = {cvtpk(sv0[0], sv0[1]), cvtpk(sv0[2], sv0[3]), cvtpk(sv1[0], sv1[1]),            \
                 cvtpk(sv1[2], sv1[3])};                                                         \
    u32x4 pd_ = {cvtpk(dv0[0], dv0[1]), cvtpk(dv0[2], dv0[3]), cvtpk(dv1[0], dv1[1]),            \
                 cvtpk(dv1[2], dv1[3])};                                                         \
    u32x4 pp_ = {cvtpk(sv0[0] * dv0[0], sv0[1] * dv0[1]), cvtpk(sv0[2] * dv0[2], sv0[3] * dv0[3]),\
                 cvtpk(sv1[0] * dv1[0], sv1[1] * dv1[1]), cvtpk(sv1[2] * dv1[2], sv1[3] * dv1[3])};\
    u32x4 pa_ = {cvtpk(fabsf(sv0[0] - dv0[0]), fabsf(sv0[1] - dv0[1])),                          \
                 cvtpk(fabsf(sv0[2] - dv0[2]), fabsf(sv0[3] - dv0[3])),                          \
                 cvtpk(fabsf(sv1[0] - dv1[0]), fabsf(sv1[1] - dv1[1])),                          \
                 cvtpk(fabsf(sv1[2] - dv1[2]), fabsf(sv1[3] - dv1[3]))};                         \
    u32x2 pc_ = {cvtpk(cv[0], cv[1]), cvtpk(cv[2], cv[3])};                                      \
    *(u32x4*)(rowp_ + ((sh * 16) ^ rswz_)) = ps_;                                                \
    *(u32x4*)(rowp_ + ((128 + sh * 16) ^ rswz_)) = pd_;                                          \
    *(u32x4*)(rowp_ + ((256 + sh * 16) ^ rswz_)) = pp_;                                          \
    *(u32x4*)(rowp_ + ((384 + sh * 16) ^ rswz_)) = pa_;                                          \
    *(u32x2*)(rowp_ + 512 + ((sh * 8) ^ rswz_)) = pc_;                                           \
  } while (0)

#define GATHER_NEXT(tg)                                                                          \
  do {                                                                                           \
    const f32x4* zs_ = (const f32x4*)(z + ((size_t)i0n * 64 + sh * 8));                          \
    sv0 = zs_[0];                                                                                \
    sv1 = zs_[1];                                                                                \
    const f32x4* zd_ = (const f32x4*)(z + ((size_t)i1n * 64 + sh * 8));                          \
    dv0 = zd_[0];                                                                                \
    dv1 = zd_[1];                                                                                \
    int eg_ = ((tg) << 7) + sr;                                                                  \
    int esg_ = eg_ < E ? eg_ : E - 1;                                                            \
    cv = *(const f32x4*)(ctx + (size_t)esg_ * 32 + sh * 4);                                      \
    int tn_ = (tg) + grid;                                                                       \
    if (tn_ >= nblk) tn_ = (tg);                                                                 \
    int en_ = (tn_ << 7) + sr;                                                                   \
    int esn_ = en_ < E ? en_ : E - 1;                                                            \
    i0n = ei[esn_];                                                                              \
    i1n = ei[E + esn_];                                                                          \
  } while (0)

__global__ __launch_bounds__(1024, 4) void fused_kernel(
    const float* __restrict__ z, const int* __restrict__ ei, const float* __restrict__ ctx,
    const unsigned short* __restrict__ w1f, const unsigned short* __restrict__ w2f,
    const float* __restrict__ sc, const float* __restrict__ w3, const float* __restrict__ b3,
    float* __restrict__ out, int E, int nblk) {
  extern __shared__ char lds[];
  char* W1L = lds;
  float* SC = (float*)(lds + LDS_SC_OFF);
  char* AR = lds + LDS_A_OFF;
  char* X1 = lds + LDS_A_OFF;  // alias: x1 overwrites A-head after L1 reads complete
  float* l3 = (float*)(lds + LDS_L3_OFF);

  const int tid = threadIdx.x;
  const int lane = tid & 63, wave = tid >> 6;
  const int g = lane >> 4, lq = lane & 15;
  const int wr = wave >> 2, wc = wave & 3;   // L1 grid 4x4: 32 rows x 32 cols per wave
  const int w2r = wave >> 1, w2c = wave & 1; // L2 grid 8x2: 16 rows x 32 cols per wave
  const int sr = tid >> 3, sh = tid & 7;     // staging: 8 threads per edge
  const int grid = gridDim.x;

  // ---- stage W1 (72 KB) + SC into LDS ----
  {
    const f32x4* s = (const f32x4*)w1f;
    f32x4* d = (f32x4*)W1L;
#pragma unroll
    for (int i = 0; i < 4; i++) d[i * 1024 + tid] = s[i * 1024 + tid];
    if (tid < 512) d[4096 + tid] = s[4096 + tid];
    if (tid < 128) {
      SC[tid] = sc[tid];
      SC[128 + tid] = sc[128 + tid];
    } else if (tid < 192) {
      int j = tid - 128;
      SC[256 + j] = sc[256 + j];
      SC[320 + j] = sc[320 + j];
      SC[384 + j] = w3[j];
    } else if (tid == 192) {
      SC[448] = b3[0];
    }
  }

  // ---- persistent W2 fragments in registers (32 VGPR) ----
  bf16x8 w2g0, w2g1, w2g2, w2g3, w2h0, w2h1, w2h2, w2h3;
  {
    const bf16x8* W2G = (const bf16x8*)w2f;
    w2g0 = W2G[(0 * 4 + w2c * 2 + 0) * 64 + lane];
    w2h0 = W2G[(0 * 4 + w2c * 2 + 1) * 64 + lane];
    w2g1 = W2G[(1 * 4 + w2c * 2 + 0) * 64 + lane];
    w2h1 = W2G[(1 * 4 + w2c * 2 + 1) * 64 + lane];
    w2g2 = W2G[(2 * 4 + w2c * 2 + 0) * 64 + lane];
    w2h2 = W2G[(2 * 4 + w2c * 2 + 1) * 64 + lane];
    w2g3 = W2G[(3 * 4 + w2c * 2 + 0) * 64 + lane];
    w2h3 = W2G[(3 * 4 + w2c * 2 + 1) * 64 + lane];
  }

  f32x4 sv0, sv1, dv0, dv1, cv;
  int i0n, i1n;
  int t = blockIdx.x;

  // ---- prologue: gather tile t, write A(t), gather t+1, prefetch ei t+2 ----
  {
    int e = (t << 7) + sr;
    int es = e < E ? e : E - 1;
    int a0 = ei[es], a1 = ei[E + es];
    cv = *(const f32x4*)(ctx + (size_t)es * 32 + sh * 4);
    const f32x4* zs = (const f32x4*)(z + ((size_t)a0 * 64 + sh * 8));
    sv0 = zs[0];
    sv1 = zs[1];
    const f32x4* zd = (const f32x4*)(z + ((size_t)a1 * 64 + sh * 8));
    dv0 = zd[0];
    dv1 = zd[1];
    int tn = t + grid;
    if (tn >= nblk) tn = t;
    int en = (tn << 7) + sr;
    int esn = en < E ? en : E - 1;
    i0n = ei[esn];
    i1n = ei[E + esn];
  }
  WRITE_A();
  {
    int tn = t + grid;
    if (tn >= nblk) tn = t;
    GATHER_NEXT(tn);
  }
  __syncthreads();  // A(t) + W1L + SC visible

  for (; t < nblk; t += grid) {
    // ---- layer 1: A[128x288] @ W1[288x128]; 2x2 16x16 frags per wave ----
    f32x4 acc00 = {0.f, 0.f, 0.f, 0.f}, acc01 = acc00, acc10 = acc00, acc11 = acc00;
    const bf16x8* W1F = (const bf16x8*)W1L;
    const int row0 = wr * 32 + lq, row1 = row0 + 16;
    const int swz0 = (row0 & 7) << 4, swz1 = (row1 & 7) << 4;
    const char* ap0 = AR + row0 * 640;
    const char* ap1 = AR + row1 * 640;
#pragma unroll
    for (int kb = 0; kb < 9; kb++) {
      bf16x8 a0 = *(const bf16x8*)(ap0 + ((kb * 64 + g * 16) ^ swz0));
      bf16x8 a1 = *(const bf16x8*)(ap1 + ((kb * 64 + g * 16) ^ swz1));
      bf16x8 b0 = W1F[(kb * 8 + wc * 2 + 0) * 64 + lane];
      bf16x8 b1 = W1F[(kb * 8 + wc * 2 + 1) * 64 + lane];
      acc00 = __builtin_amdgcn_mfma_f32_16x16x32_bf16(a0, b0, acc00, 0, 0, 0);
      acc01 = __builtin_amdgcn_mfma_f32_16x16x32_bf16(a0, b1, acc01, 0, 0, 0);
      acc10 = __builtin_amdgcn_mfma_f32_16x16x32_bf16(a1, b0, acc10, 0, 0, 0);
      acc11 = __builtin_amdgcn_mfma_f32_16x16x32_bf16(a1, b1, acc11, 0, 0, 0);
    }
    __syncthreads();  // all waves done reading A(t); X1 alias region now writable

    // ---- x1-write(t): bn+relu, packed u32 stores at permuted slots ----
    {
      const int col0 = wc * 32 + lq, col1 = col0 + 16;
      const float s1v0 = SC[col0], c1v0 = SC[128 + col0];
      const float s1v1 = SC[col1], c1v1 = SC[128 + col1];
      const int xoff = wc * 64 + lq * 4;  // physical slot pair (nf=0,nf=1) adjacent
#pragma unroll
      for (int j = 0; j < 4; j++) {
        int rowa = wr * 32 + 4 * g + j;
        unsigned int pA = cvtpk(fmaxf(acc00[j] * s1v0 + c1v0, 0.f),
                                fmaxf(acc01[j] * s1v1 + c1v1, 0.f));
        *(unsigned int*)(X1 + rowa * 256 + (xoff ^ ((rowa & 7) << 4))) = pA;
        int rowb = rowa + 16;
        unsigned int pB = cvtpk(fmaxf(acc10[j] * s1v0 + c1v0, 0.f),
                                fmaxf(acc11[j] * s1v1 + c1v1, 0.f));
        *(unsigned int*)(X1 + rowb * 256 + (xoff ^ ((rowb & 7) << 4))) = pB;
      }
    }
    __syncthreads();  // x1(t) visible

    // ---- layer 2: x1[128x128] @ W2[128x64]; 1x2 frags per wave, W2 from regs ----
    f32x4 acc2A = {0.f, 0.f, 0.f, 0.f}, acc2B = acc2A;
    {
      const int row = w2r * 16 + lq;
      const int swz = (row & 7) << 4;
      const char* xp = X1 + row * 256;
      bf16x8 a0 = *(const bf16x8*)(xp + ((0 * 64 + g * 16) ^ swz));
      acc2A = __builtin_amdgcn_mfma_f32_16x16x32_bf16(a0, w2g0, acc2A, 0, 0, 0);
      acc2B = __builtin_amdgcn_mfma_f32_16x16x32_bf16(a0, w2h0, acc2B, 0, 0, 0);
      bf16x8 a1 = *(const bf16x8*)(xp + ((1 * 64 + g * 16) ^ swz));
      acc2A = __builtin_amdgcn_mfma_f32_16x16x32_bf16(a1, w2g1, acc2A, 0, 0, 0);
      acc2B = __builtin_amdgcn_mfma_f32_16x16x32_bf16(a1, w2h1, acc2B, 0, 0, 0);
      bf16x8 a2 = *(const bf16x8*)(xp + ((2 * 64 + g * 16) ^ swz));
      acc2A = __builtin_amdgcn_mfma_f32_16x16x32_bf16(a2, w2g2, acc2A, 0, 0, 0);
      acc2B = __builtin_amdgcn_mfma_f32_16x16x32_bf16(a2, w2h2, acc2B, 0, 0, 0);
      bf16x8 a3 = *(const bf16x8*)(xp + ((3 * 64 + g * 16) ^ swz));
      acc2A = __builtin_amdgcn_mfma_f32_16x16x32_bf16(a3, w2g3, acc2A, 0, 0, 0);
      acc2B = __builtin_amdgcn_mfma_f32_16x16x32_bf16(a3, w2h3, acc2B, 0, 0, 0);
    }

    // ---- layer 3: bn+relu, dot w3, 16-lane shfl reduce ----
    const int colA = w2c * 32 + lq, colB = colA + 16;
    const float s2A = SC[256 + colA], c2A = SC[320 + colA];
    const float s2B = SC[256 + colB], c2B = SC[320 + colB];
    const float w3A = SC[384 + colA], w3B = SC[384 + colB];
#pragma unroll
    for (int j = 0; j < 4; j++) {
      float vA = fmaxf(acc2A[j] * s2A + c2A, 0.f);
      float vB = fmaxf(acc2B[j] * s2B + c2B, 0.f);
      float p = vA * w3A + vB * w3B;
      p += __shfl_xor(p, 1);
      p += __shfl_xor(p, 2);
      p += __shfl_xor(p, 4);
      p += __shfl_xor(p, 8);
      if (lq == 0) l3[(w2r * 16 + 4 * g + j) * 2 + w2c] = p;
    }
    __syncthreads();  // l3 visible; all x1 reads done -> A region writable

    // ---- phase 4: A-write(t+1) | issue gathers(t+2) | out(t) ----
    WRITE_A();  // consumes t+1 gather regs
    {
      int tn2 = t + 2 * grid;
      if (tn2 >= nblk) tn2 = t + grid < nblk ? t + grid : t;
      GATHER_NEXT(tn2);  // long-latency loads; land during next L1
    }
    if (tid < 128) {
      int e = (t << 7) + tid;
      if (e < E) out[e] = l3[tid * 2] + l3[tid * 2 + 1] + SC[448];
    }
    __syncthreads();  // A(t+1) visible
  }
}

extern "C" void kernel_launch(void* const* d_in, const int* in_sizes, int n_in,
                              void* d_out, int out_size, void* d_ws, size_t ws_size,
                              hipStream_t stream) {
  const float* z = (const float*)d_in[0];
  const int* ei = (const int*)d_in[1];
  const float* ctx = (const float*)d_in[2];
  const float* W1 = (const float*)d_in[3];
  const float* b1 = (const float*)d_in[4];
  const float* g1 = (const float*)d_in[5];
  const float* be1 = (const float*)d_in[6];
  const float* m1 = (const float*)d_in[7];
  const float* v1 = (const float*)d_in[8];
  const float* W2 = (const float*)d_in[9];
  const float* b2 = (const float*)d_in[10];
  const float* g2 = (const float*)d_in[11];
  const float* be2 = (const float*)d_in[12];
  const float* m2 = (const float*)d_in[13];
  const float* v2 = (const float*)d_in[14];
  const float* W3 = (const float*)d_in[15];
  const float* b3 = (const float*)d_in[16];
  float* out = (float*)d_out;
  const int E = out_size;

  unsigned short* w1f = (unsigned short*)d_ws;
  unsigned short* w2f = (unsigned short*)((char*)d_ws + 73728);
  float* sc = (float*)((char*)d_ws + 90112);

  prep_kernel<<<177, 256, 0, stream>>>(W1, W2, b1, g1, be1, m1, v1,
                                       b2, g2, be2, m2, v2, w1f, w2f, sc);

  const int nblk = (E + 127) >> 7;
  (void)hipFuncSetAttribute((const void*)fused_kernel,
                            hipFuncAttributeMaxDynamicSharedMemorySize, LDS_TOTAL);
  fused_kernel<<<256, 1024, LDS_TOTAL, stream>>>(z, ei, ctx, w1f, w2f, sc, W3, b3,
                                                 out, E, nblk);
}